// Round 6
// baseline (153.621 us; speedup 1.0000x reference)
//
#include <hip/hip_runtime.h>
#include <math.h>

// GreyBoxTargetedDropout: rows=65536, cols=1024, P=0.1, PERCENT_DROP=0.5.
// Budget exhausted by eligible rows -> reference's random branch is dead.
//   k_elig_count: per-256-row-chunk eligible counts (ballot).
//   k_compute_k : each block redundantly scans chunk counts -> karr.
//   k_apply (fused, block-per-row): k==0 -> streaming scale (nontemporal);
//     k>0 -> radix select: 2 barriers/pass (dbuf hist + wave-redundant scan),
//            cnt<=32 candidate-gather exit, pre-aggregated pass atomics,
//            conditional stable-tie path.

#define COLS 1024

typedef float f32x4 __attribute__((ext_vector_type(4)));

static __device__ __forceinline__ unsigned int fkey(float f) {
  unsigned int u = __float_as_uint(f);
  return (u & 0x80000000u) ? ~u : (u | 0x80000000u);
}

// ---- pass 1: per-chunk eligible-row counts (ballot) -----------------------
__global__ __launch_bounds__(256) void k_elig_count(
    const int* __restrict__ labels, const int* __restrict__ tc, int ntc,
    int rows, int* __restrict__ partial) {
  const int t = threadIdx.x;
  const int row = blockIdx.x * 256 + t;
  int e = 0;
  if (row < rows) {
    int lab = labels[row];
    for (int j = 0; j < ntc; ++j) e |= (lab == tc[j]) ? 1 : 0;
  }
  unsigned long long m = __ballot(e);
  __shared__ int wc[4];
  if ((t & 63) == 0) wc[t >> 6] = __popcll(m);
  __syncthreads();
  if (t == 0) partial[blockIdx.x] = wc[0] + wc[1] + wc[2] + wc[3];
}

// ---- pass 2: per-row k_i (each block scans all partials redundantly) ------
__global__ __launch_bounds__(256) void k_compute_k(
    const int* __restrict__ labels, const int* __restrict__ tc, int ntc,
    const int* __restrict__ partial, int nchunks, int rows,
    long long ntz, int kpr, int* __restrict__ karr) {
  const int t = threadIdx.x;
  const int lane = t & 63, wid = t >> 6;

  __shared__ int ws[4];
  __shared__ int soff[256];
  __shared__ int wcnt[4];

  int pv = (t < nchunks) ? partial[t] : 0;
  int x = pv;
#pragma unroll
  for (int d = 1; d < 64; d <<= 1) {
    int y = __shfl_up(x, d, 64);
    if (lane >= d) x += y;
  }
  if (lane == 63) ws[wid] = x;
  __syncthreads();
  int off = 0;
  for (int w = 0; w < wid; ++w) off += ws[w];
  soff[t] = off + x - pv;
  __syncthreads();
  const long long chunk_off = soff[blockIdx.x];

  const int row = blockIdx.x * 256 + t;
  int e = 0;
  if (row < rows) {
    int lab = labels[row];
    for (int j = 0; j < ntc; ++j) e |= (lab == tc[j]) ? 1 : 0;
  }
  unsigned long long m = __ballot(e);
  int lanepre = __popcll(m & ((1ull << lane) - 1ull));
  if (lane == 0) wcnt[wid] = __popcll(m);
  __syncthreads();
  int wpre = 0;
  for (int w = 0; w < wid; ++w) wpre += wcnt[w];

  long long elig_before = chunk_off + wpre + lanepre;
  long long zb = elig_before * (long long)kpr;
  if (zb > ntz) zb = ntz;
  long long rem = ntz - zb;
  int ki = 0;
  if (e) {
    if (rem < 0) rem = 0;
    ki = (rem > (long long)kpr) ? kpr : (int)rem;
  }
  if (row < rows) karr[row] = ki;
}

// ---- main: fused block-per-row; streaming scale OR radix select -----------
__global__ __launch_bounds__(256) void k_apply(
    const float* __restrict__ in, float* __restrict__ out,
    const int* __restrict__ karr, float scale) {
  const int t = threadIdx.x;
  const int lane = t & 63;
  const int row = blockIdx.x;
  const int k = karr[row];

  const f32x4* in4 = (const f32x4*)(in + (size_t)row * COLS);
  f32x4* out4 = (f32x4*)(out + (size_t)row * COLS);
  f32x4 v = __builtin_nontemporal_load(&in4[t]);

  if (k == 0) {  // block-uniform: pure streaming scale
    v *= scale;
    __builtin_nontemporal_store(v, &out4[t]);
    return;
  }

  __shared__ int hist2[2][256];
  __shared__ unsigned int cand[32];
  __shared__ int s_nc;
  __shared__ __align__(16) unsigned int skeys[1024];

  unsigned int key[4] = {fkey(v.x), fkey(v.y), fkey(v.z), fkey(v.w)};

  hist2[0][t] = 0;
  hist2[1][t] = 0;
  if (t == 0) s_nc = 0;
  __syncthreads();

  unsigned int prefix = 0, kth = 0;
  int krem = k, cnt = 0;
  bool resolved = false;

#pragma unroll 1
  for (int pass = 0; pass < 4; ++pass) {
    const int shift = 24 - 8 * pass;
    const unsigned int pmask = (pass == 0) ? 0u : (0xFFFFFFFFu << (shift + 8));
    int* h = hist2[pass & 1];

    // per-thread pre-aggregated histogram atomics
    unsigned int bj[4]; int cj[4]; bool live[4];
#pragma unroll
    for (int j = 0; j < 4; ++j) {
      live[j] = ((key[j] & pmask) == prefix);
      bj[j] = live[j] ? ((key[j] >> shift) & 0xFFu) : 0xFFFFFFFFu;
      cj[j] = 1;
    }
#pragma unroll
    for (int j = 1; j < 4; ++j) {
      if (live[j]) {
#pragma unroll
        for (int i = 0; i < j; ++i) {
          if (live[i] && bj[i] == bj[j]) { cj[i] += 1; live[j] = false; break; }
        }
      }
    }
#pragma unroll
    for (int j = 0; j < 4; ++j)
      if (live[j]) atomicAdd(&h[bj[j]], cj[j]);

    __syncthreads();                       // S1: hist complete
    hist2[(pass + 1) & 1][t] = 0;          // zero other buffer for next pass

    // wave-redundant scan of all 256 buckets (4 consecutive per lane)
    int b0 = h[4 * lane + 0], b1 = h[4 * lane + 1];
    int b2 = h[4 * lane + 2], b3 = h[4 * lane + 3];
    int c0 = b0, c1 = c0 + b1, c2 = c1 + b2, c3 = c2 + b3;
    int x = c3;
#pragma unroll
    for (int d = 1; d < 64; d <<= 1) {
      int y = __shfl_up(x, d, 64);
      if (lane >= d) x += y;
    }
    int incl = x, excl = x - c3;
    unsigned long long m = __ballot(excl < krem && krem <= incl);
    int src = __ffsll(m) - 1;
    int excl_sel = __shfl(excl, src, 64);
    int cc0 = __shfl(c0, src, 64), cc1 = __shfl(c1, src, 64);
    int cc2 = __shfl(c2, src, 64), cc3 = __shfl(c3, src, 64);
    int sub = (krem > excl_sel + cc0 ? 1 : 0) +
              (krem > excl_sel + cc1 ? 1 : 0) +
              (krem > excl_sel + cc2 ? 1 : 0);
    int pm1 = (sub == 0) ? 0 : ((sub == 1) ? cc0 : ((sub == 2) ? cc1 : cc2));
    int cm  = (sub == 0) ? cc0 : ((sub == 1) ? cc1 : ((sub == 2) ? cc2 : cc3));
    prefix |= ((unsigned int)(4 * src + sub)) << shift;
    krem -= excl_sel + pm1;
    cnt = cm - pm1;

    if (cnt <= 32 && pass < 3) {
      // gather the cnt candidates sharing prefix; resolve rank directly
      const unsigned int mk = 0xFFFFFFFFu << shift;
#pragma unroll
      for (int j = 0; j < 4; ++j) {
        if ((key[j] & mk) == prefix) {
          int s = atomicAdd(&s_nc, 1);
          cand[s] = key[j];
        }
      }
      __syncthreads();                     // candidates gathered
      // redundant O(cnt^2) rank-select of the krem-th smallest (with dups)
      unsigned int K = 0; int nless = 0, neq = 0;
      for (int i = 0; i < cnt; ++i) {
        unsigned int ci = cand[i];
        int li = 0, ei = 0;
        for (int j2 = 0; j2 < cnt; ++j2) {
          unsigned int c2v = cand[j2];
          li += (c2v < ci) ? 1 : 0;
          ei += (c2v == ci) ? 1 : 0;
        }
        if (li < krem && krem <= li + ei) { K = ci; nless = li; neq = ei; }
      }
      kth = K;
      krem -= nless;
      cnt = neq;
      resolved = true;
      break;
    }
    __syncthreads();                       // S2: zeroed hist visible for next pass
  }

  if (!resolved) kth = prefix;             // full 32 bits resolved by pass 4
  const bool need_stable = (krem != cnt);  // block-uniform; ~never true
  if (need_stable) {
    ((uint4*)skeys)[t] = make_uint4(key[0], key[1], key[2], key[3]);
    __syncthreads();
  }

  const float vv[4] = {v.x, v.y, v.z, v.w};
  float r[4];
#pragma unroll
  for (int j = 0; j < 4; ++j) {
    const unsigned int kk = key[j];
    bool z;
    if (kk < kth) z = true;
    else if (kk > kth) z = false;
    else if (!need_stable) z = true;  // zero all ties (krem == tie count)
    else {
      int idx = 4 * t + j;
      int c2 = 0;
      for (int i = 0; i < idx; ++i) c2 += (skeys[i] == kth) ? 1 : 0;
      z = (c2 < krem);
    }
    r[j] = z ? 0.0f : vv[j] * scale;
  }
  f32x4 o = {r[0], r[1], r[2], r[3]};
  __builtin_nontemporal_store(o, &out4[t]);
}

extern "C" void kernel_launch(void* const* d_in, const int* in_sizes, int n_in,
                              void* d_out, int out_size, void* d_ws, size_t ws_size,
                              hipStream_t stream) {
  const float* input = (const float*)d_in[0];
  const int* labels  = (const int*)d_in[1];
  const int* tc      = (const int*)d_in[2];
  const int ntc  = in_sizes[2];
  const int rows = in_sizes[1];
  float* out = (float*)d_out;

  const int nchunks = (rows + 255) / 256;  // 256 for rows=65536
  int* partial = (int*)d_ws;
  int* karr    = partial + nchunks;

  const long long nodes_to_zero =
      (long long)floor((double)rows * (double)COLS * 0.1);
  const int k_per_row = (int)floor((double)COLS * 0.5);
  const float scale = (float)(1.0 / (1.0 - 0.1));

  hipLaunchKernelGGL(k_elig_count, dim3(nchunks), dim3(256), 0, stream,
                     labels, tc, ntc, rows, partial);
  hipLaunchKernelGGL(k_compute_k, dim3(nchunks), dim3(256), 0, stream,
                     labels, tc, ntc, partial, nchunks, rows,
                     nodes_to_zero, k_per_row, karr);
  hipLaunchKernelGGL(k_apply, dim3(rows), dim3(256), 0, stream,
                     input, out, karr, scale);
}

// Round 7
// 104.137 us; speedup vs baseline: 1.4752x; 1.4752x over previous
//
#include <hip/hip_runtime.h>
#include <math.h>

// GreyBoxTargetedDropout: rows=65536, cols=1024, P=0.1, PERCENT_DROP=0.5.
// Budget exhausted by eligible rows -> reference's random branch is dead.
//   k_elig_count: per-256-row-chunk eligible counts (ballot).       [r5 verbatim]
//   k_compute_k : per-row k_i, redundant chunk-scan per block.      [r5 verbatim]
//   k_apply     : 4 rows per block. All row-slices loaded up front (MLP=4);
//                 k==0 rows stream out immediately; k>0 rows run the r5
//                 radix-select (unchanged internals) sequentially.

#define COLS 1024

typedef float f32x4 __attribute__((ext_vector_type(4)));

static __device__ __forceinline__ unsigned int fkey(float f) {
  unsigned int u = __float_as_uint(f);
  return (u & 0x80000000u) ? ~u : (u | 0x80000000u);
}

// ---- pass 1: per-chunk eligible-row counts (ballot) -----------------------
__global__ __launch_bounds__(256) void k_elig_count(
    const int* __restrict__ labels, const int* __restrict__ tc, int ntc,
    int rows, int* __restrict__ partial) {
  const int t = threadIdx.x;
  const int row = blockIdx.x * 256 + t;
  int e = 0;
  if (row < rows) {
    int lab = labels[row];
    for (int j = 0; j < ntc; ++j) e |= (lab == tc[j]) ? 1 : 0;
  }
  unsigned long long m = __ballot(e);
  __shared__ int wc[4];
  if ((t & 63) == 0) wc[t >> 6] = __popcll(m);
  __syncthreads();
  if (t == 0) partial[blockIdx.x] = wc[0] + wc[1] + wc[2] + wc[3];
}

// ---- pass 2: per-row k_i (each block scans all partials redundantly) ------
__global__ __launch_bounds__(256) void k_compute_k(
    const int* __restrict__ labels, const int* __restrict__ tc, int ntc,
    const int* __restrict__ partial, int nchunks, int rows,
    long long ntz, int kpr, int* __restrict__ karr) {
  const int t = threadIdx.x;
  const int lane = t & 63, wid = t >> 6;

  __shared__ int ws[4];
  __shared__ int soff[256];
  __shared__ int wcnt[4];

  int pv = (t < nchunks) ? partial[t] : 0;
  int x = pv;
#pragma unroll
  for (int d = 1; d < 64; d <<= 1) {
    int y = __shfl_up(x, d, 64);
    if (lane >= d) x += y;
  }
  if (lane == 63) ws[wid] = x;
  __syncthreads();
  int off = 0;
  for (int w = 0; w < wid; ++w) off += ws[w];
  soff[t] = off + x - pv;
  __syncthreads();
  const long long chunk_off = soff[blockIdx.x];

  const int row = blockIdx.x * 256 + t;
  int e = 0;
  if (row < rows) {
    int lab = labels[row];
    for (int j = 0; j < ntc; ++j) e |= (lab == tc[j]) ? 1 : 0;
  }
  unsigned long long m = __ballot(e);
  int lanepre = __popcll(m & ((1ull << lane) - 1ull));
  if (lane == 0) wcnt[wid] = __popcll(m);
  __syncthreads();
  int wpre = 0;
  for (int w = 0; w < wid; ++w) wpre += wcnt[w];

  long long elig_before = chunk_off + wpre + lanepre;
  long long zb = elig_before * (long long)kpr;
  if (zb > ntz) zb = ntz;
  long long rem = ntz - zb;
  int ki = 0;
  if (e) {
    if (rem < 0) rem = 0;
    ki = (rem > (long long)kpr) ? kpr : (int)rem;
  }
  if (row < rows) karr[row] = ki;
}

// ---- r5's block-wide radix select, verbatim internals ---------------------
// Selects & zeroes the k smallest of the 1024 values (v = this thread's 4),
// scales the rest, stores to outp[t]. Block-uniform k > 0.
__device__ __forceinline__ void select_row(
    f32x4 v, int k, int t, f32x4* __restrict__ outp, float scale,
    int* __restrict__ hist, int* __restrict__ wsum,
    int* __restrict__ s_i, unsigned int* __restrict__ s_kth,
    unsigned int* __restrict__ skeys) {
  unsigned int key[4] = {fkey(v.x), fkey(v.y), fkey(v.z), fkey(v.w)};

  unsigned int prefix = 0;
  int krem = k;
  int cnt = 0;
  bool done = false;

  hist[t] = 0;
  __syncthreads();

#pragma unroll 1
  for (int pass = 0; pass < 4 && !done; ++pass) {
    const int shift = 24 - 8 * pass;
    const unsigned int pmask = (pass == 0) ? 0u : (0xFFFFFFFFu << (shift + 8));
#pragma unroll
    for (int j = 0; j < 4; ++j) {
      if ((key[j] & pmask) == prefix)
        atomicAdd(&hist[(key[j] >> shift) & 0xFF], 1);
    }
    __syncthreads();                       // S1: atomics done
    int h = hist[t];
    hist[t] = 0;                           // re-zero for next pass / next row
    int x = h;                             // 64-lane inclusive scan
#pragma unroll
    for (int d = 1; d < 64; d <<= 1) {
      int y = __shfl_up(x, d, 64);
      if ((t & 63) >= d) x += y;
    }
    if ((t & 63) == 63) wsum[t >> 6] = x;
    __syncthreads();                       // S2: wsum ready, hist zeroed
    int off = 0;
    for (int w = 0; w < (t >> 6); ++w) off += wsum[w];
    int incl = off + x;
    int excl = incl - h;
    if (excl < krem && krem <= incl) { s_i[0] = t; s_i[1] = excl; s_i[2] = h; }
    __syncthreads();                       // S3: s_* ready
    prefix |= ((unsigned int)s_i[0]) << shift;
    krem -= s_i[1];
    cnt = s_i[2];
    if (cnt == 1 && pass < 3) {
      // unique element carries the kth key: broadcast it, skip later passes
      const unsigned int m = 0xFFFFFFFFu << shift;
#pragma unroll
      for (int j = 0; j < 4; ++j)
        if ((key[j] & m) == prefix) s_kth[0] = key[j];
      __syncthreads();
      prefix = s_kth[0];
      done = true;
    }
  }

  const unsigned int kth = prefix;        // exact key of k-th smallest
  const bool need_stable = (krem != cnt); // block-uniform; ~never true
  if (need_stable) {
    ((uint4*)skeys)[t] = make_uint4(key[0], key[1], key[2], key[3]);
    __syncthreads();
  }

  const float vv[4] = {v.x, v.y, v.z, v.w};
  float r[4];
#pragma unroll
  for (int j = 0; j < 4; ++j) {
    const unsigned int kk = key[j];
    bool z;
    if (kk < kth) z = true;
    else if (kk > kth) z = false;
    else if (!need_stable) z = true;  // zero all ties (krem == tie count)
    else {
      int idx = 4 * t + j;
      int c2 = 0;
      for (int i = 0; i < idx; ++i) c2 += (skeys[i] == kth) ? 1 : 0;
      z = (c2 < krem);
    }
    r[j] = z ? 0.0f : vv[j] * scale;
  }
  f32x4 o = {r[0], r[1], r[2], r[3]};
  __builtin_nontemporal_store(o, &outp[t]);
}

// ---- main: 4 rows per block -----------------------------------------------
__global__ __launch_bounds__(256) void k_apply(
    const float* __restrict__ in, float* __restrict__ out,
    const int* __restrict__ karr, float scale, int rows) {
  const int t = threadIdx.x;
  const int r0 = blockIdx.x * 4;

  __shared__ int hist[256];
  __shared__ int wsum[4];
  __shared__ int s_i[3];
  __shared__ unsigned int s_kth[1];
  __shared__ __align__(16) unsigned int skeys[1024];

  const bool ok1 = (r0 + 1) < rows, ok2 = (r0 + 2) < rows, ok3 = (r0 + 3) < rows;
  const int k0 = karr[r0];
  const int k1 = ok1 ? karr[r0 + 1] : 0;
  const int k2 = ok2 ? karr[r0 + 2] : 0;
  const int k3 = ok3 ? karr[r0 + 3] : 0;

  const f32x4* in4 = (const f32x4*)(in + (size_t)r0 * COLS);
  f32x4* out4 = (f32x4*)(out + (size_t)r0 * COLS);

  // issue all four row-slices up front (4 outstanding loads per thread)
  f32x4 v0 = __builtin_nontemporal_load(&in4[0 * 256 + t]);
  f32x4 v1, v2, v3;
  if (ok1) v1 = __builtin_nontemporal_load(&in4[1 * 256 + t]);
  if (ok2) v2 = __builtin_nontemporal_load(&in4[2 * 256 + t]);
  if (ok3) v3 = __builtin_nontemporal_load(&in4[3 * 256 + t]);

  // streaming stores for k==0 rows (block-uniform branches)
  if (k0 == 0) __builtin_nontemporal_store(v0 * scale, &out4[0 * 256 + t]);
  if (ok1 && k1 == 0) __builtin_nontemporal_store(v1 * scale, &out4[1 * 256 + t]);
  if (ok2 && k2 == 0) __builtin_nontemporal_store(v2 * scale, &out4[2 * 256 + t]);
  if (ok3 && k3 == 0) __builtin_nontemporal_store(v3 * scale, &out4[3 * 256 + t]);

  if ((k0 | k1 | k2 | k3) == 0) return;

  // block-wide select for k>0 rows, sequential (r5 internals verbatim)
  if (k0 > 0) select_row(v0, k0, t, &out4[0 * 256], scale, hist, wsum, s_i, s_kth, skeys);
  if (k1 > 0) select_row(v1, k1, t, &out4[1 * 256], scale, hist, wsum, s_i, s_kth, skeys);
  if (k2 > 0) select_row(v2, k2, t, &out4[2 * 256], scale, hist, wsum, s_i, s_kth, skeys);
  if (k3 > 0) select_row(v3, k3, t, &out4[3 * 256], scale, hist, wsum, s_i, s_kth, skeys);
}

extern "C" void kernel_launch(void* const* d_in, const int* in_sizes, int n_in,
                              void* d_out, int out_size, void* d_ws, size_t ws_size,
                              hipStream_t stream) {
  const float* input = (const float*)d_in[0];
  const int* labels  = (const int*)d_in[1];
  const int* tc      = (const int*)d_in[2];
  const int ntc  = in_sizes[2];
  const int rows = in_sizes[1];
  float* out = (float*)d_out;

  const int nchunks = (rows + 255) / 256;  // 256 for rows=65536
  int* partial = (int*)d_ws;
  int* karr    = partial + nchunks;

  const long long nodes_to_zero =
      (long long)floor((double)rows * (double)COLS * 0.1);
  const int k_per_row = (int)floor((double)COLS * 0.5);
  const float scale = (float)(1.0 / (1.0 - 0.1));

  hipLaunchKernelGGL(k_elig_count, dim3(nchunks), dim3(256), 0, stream,
                     labels, tc, ntc, rows, partial);
  hipLaunchKernelGGL(k_compute_k, dim3(nchunks), dim3(256), 0, stream,
                     labels, tc, ntc, partial, nchunks, rows,
                     nodes_to_zero, k_per_row, karr);
  hipLaunchKernelGGL(k_apply, dim3((rows + 3) / 4), dim3(256), 0, stream,
                     input, out, karr, scale, rows);
}